// Round 9
// baseline (10414.545 us; speedup 1.0000x reference)
//
#include <hip/hip_runtime.h>
#include <cmath>

typedef __attribute__((ext_vector_type(8))) short short8;
typedef __attribute__((ext_vector_type(4))) float f32x4;

#define B_SZ 512
#define T_SZ 256
#define I_SZ 256
#define H_SZ 1024
#define V_SZ 1024
#define E_SZ 8
#define FUT 64

// R5 numerics (3-product split-bf16). Physical A / virtual W layouts:
// enc A phys: [x_hi 256 | x_lo 256 | h_hi 1024 | h_lo 1024]          = 2560
// dec A phys: [xc 128 (hi8|hi8|lo8|0) | h_hi 1024 | h_lo 1024]       = 2176
// W_enc virt: [Wih_hi|Wih_lo|Wih_hi | Whh_hi|Whh_lo|Whh_hi]          = 3840
// W_dec virt: [Wxc 128 | Whh_hi|Whh_lo|Whh_hi | 0-pad 128]           = 3328
// W_fc  virt: [Wfc_hi | Wfc_lo | Wfc_hi]                             = 3072
#define KVE 3840
#define KVD 3328
#define KVF 3072
#define APE 2560
#define APD 2176

static __device__ __forceinline__ ushort f2bf(float v) {
    uint32_t u = __float_as_uint(v);
    uint32_t r = (u + 0x7fffu + ((u >> 16) & 1u)) >> 16;
    return (ushort)r;
}
static __device__ __forceinline__ float bf2f(ushort b) {
    return __uint_as_float(((uint32_t)b) << 16);
}

#define GLD16(gp, lp)                                                          \
    __builtin_amdgcn_global_load_lds(                                         \
        (const __attribute__((address_space(1))) void*)(gp),                  \
        (__attribute__((address_space(3))) void*)(lp), 16, 0, 0)

// ---------------------------------------------------------------------------
// Split-bf16 GEMM step. Block tile 64x64, 4 waves (2m x 2n), wave tile 32x32.
// BK=64. Both operands staged via global_load_lds into 4 rotating buffers
// (64 KB total -> 2 blocks/CU, 8 waves/CU). Counted-vmcnt pipeline: stage
// k-tile p+3 while computing p; steady-state wait = vmcnt(8) (stage p done,
// 2 stages in flight) -- no vmcnt(0) drain inside the loop.
// LDS rows: 64 bf16 = 128B = 8 16B-slots, XOR-swizzled slot^(row&7); global
// source column pre-swizzled, ds_read applies the same XOR (T2, rule #21).
// A's virtual K deduped by piecewise source offset (64-aligned boundaries).
// ---------------------------------------------------------------------------
template<int NTPX, int NK, int T1, int T2, int O0, int O1, int O2, bool GATES>
__global__ __launch_bounds__(256) void gemm_step(
    const ushort* __restrict__ A, int astr,
    const ushort* __restrict__ W, int kv,
    const float* __restrict__ bias,
    float* __restrict__ c,
    ushort* __restrict__ hdest, int ldh,
    const float* __restrict__ xsrc, ushort* __restrict__ xdest,
    float* __restrict__ out, int ldo)
{
    // [0,16384): A bufs 0..3 (4 x 8 KB); [16384,32768): W bufs 0..3.
    __shared__ __align__(16) ushort lds[32768];   // 64 KB

    const int tid = threadIdx.x;
    const int lane = tid & 63;
    const int wid = tid >> 6;
    const int wm = wid >> 1, wn = wid & 1;
    const int l15 = lane & 15, lq = lane >> 4;
    const int l7 = lane & 7, l3 = lane >> 3;

    const int flat = blockIdx.x;
    const int xcd = flat & 7, slot = flat >> 3;
    const int n_tile = xcd * NTPX + (slot % NTPX);
    const int m_tile = slot / NTPX;
    const int m0 = m_tile * 64;
    const int n0 = n_tile * 64;

    f32x4 acc[2][2];
#pragma unroll
    for (int m = 0; m < 2; ++m)
#pragma unroll
        for (int n = 0; n < 2; ++n) { f32x4 z = {0.f, 0.f, 0.f, 0.f}; acc[m][n] = z; }

    // Stage k-tile p (64 cols of A and W) into buffer bufi. 4 GLD16/wave.
    auto STAGE = [&](int p, int bufi) {
        const int off = p < T1 ? O0 : (p < T2 ? O1 : O2);
        const int kc = p * 64;
        ushort* ab = &lds[bufi * 4096];
        ushort* wb = &lds[16384 + bufi * 4096];
#pragma unroll
        for (int i = 0; i < 2; ++i) {
            const int rowg = (i * 4 + wid) * 8;    // 8-row group base
            const int row = rowg + l3;
            GLD16(W + (size_t)(n0 + row) * kv + kc + ((l7 ^ l3) * 8),
                  wb + rowg * 64);
            GLD16(A + (size_t)(m0 + row) * astr + kc + off + ((l7 ^ l3) * 8),
                  ab + rowg * 64);
        }
    };
    auto COMPUTE = [&](int bufi) {
        const ushort* ab = &lds[bufi * 4096];
        const ushort* wb = &lds[16384 + bufi * 4096];
#pragma unroll
        for (int kk = 0; kk < 2; ++kk) {
            short8 af[2], wf[2];
#pragma unroll
            for (int m = 0; m < 2; ++m) {
                const int row = wm * 32 + m * 16 + l15;
                af[m] = *(const short8*)
                    &ab[row * 64 + (((kk * 4 + lq) ^ (row & 7)) * 8)];
            }
#pragma unroll
            for (int n = 0; n < 2; ++n) {
                const int row = wn * 32 + n * 16 + l15;
                wf[n] = *(const short8*)
                    &wb[row * 64 + (((kk * 4 + lq) ^ (row & 7)) * 8)];
            }
#pragma unroll
            for (int m = 0; m < 2; ++m)
#pragma unroll
                for (int n = 0; n < 2; ++n)
                    acc[m][n] = __builtin_amdgcn_mfma_f32_16x16x32_bf16(
                        af[m], wf[n], acc[m][n], 0, 0, 0);
        }
    };

    // ---- pipelined k-loop (NK % 4 == 0 for all instances) ----
    STAGE(0, 0); STAGE(1, 1); STAGE(2, 2);
#pragma unroll 1
    for (int p0 = 0; p0 < NK; p0 += 4) {
#pragma unroll
        for (int j = 0; j < 4; ++j) {
            const int p = p0 + j;
            // wait: stage p complete. in-flight stages = p..min(p+2,NK-1).
            if (p + 2 < NK)      asm volatile("s_waitcnt vmcnt(8)" ::: "memory");
            else if (p + 1 < NK) asm volatile("s_waitcnt vmcnt(4)" ::: "memory");
            else                 asm volatile("s_waitcnt vmcnt(0)" ::: "memory");
            __builtin_amdgcn_s_barrier();
            if (p + 3 < NK) STAGE(p + 3, (j + 3) & 3);
            COMPUTE(j);
        }
    }

    // --- epilogue ----------------------------------------------------------
    if constexpr (GATES) {
        float* zs = (float*)&lds[0];          // 64*65*4 = 16.6 KB <= 64 KB
        __syncthreads();
#pragma unroll
        for (int m = 0; m < 2; ++m)
#pragma unroll
            for (int n = 0; n < 2; ++n)
#pragma unroll
                for (int r = 0; r < 4; ++r)
                    zs[(wm * 32 + m * 16 + lq * 4 + r) * 65 +
                       wn * 32 + n * 16 + l15] = acc[m][n][r];
        __syncthreads();

        const int row = tid & 63;
        const int jl0 = (tid >> 6) * 4;
        const int grow = m0 + row;
        const int jg = n_tile * 16 + jl0;
        const f32x4 bi4 = *(const f32x4*)&bias[n0 + jl0];
        const f32x4 bf4 = *(const f32x4*)&bias[n0 + 16 + jl0];
        const f32x4 bg4 = *(const f32x4*)&bias[n0 + 32 + jl0];
        const f32x4 bo4 = *(const f32x4*)&bias[n0 + 48 + jl0];
        f32x4 cv = *(f32x4*)&c[(size_t)grow * H_SZ + jg];
        ushort hh[4], hl[4];
#pragma unroll
        for (int jj = 0; jj < 4; ++jj) {
            const float zi = zs[row * 65 + jl0 + jj] + bi4[jj];
            const float zf = zs[row * 65 + 16 + jl0 + jj] + bf4[jj];
            const float zg = zs[row * 65 + 32 + jl0 + jj] + bg4[jj];
            const float zo = zs[row * 65 + 48 + jl0 + jj] + bo4[jj];
            const float ig = 1.f / (1.f + expf(-zi));
            const float fg = 1.f / (1.f + expf(-zf));
            const float gg = tanhf(zg);
            const float og = 1.f / (1.f + expf(-zo));
            const float cn = fg * cv[jj] + ig * gg;
            cv[jj] = cn;
            const float hv = og * tanhf(cn);
            hh[jj] = f2bf(hv);
            hl[jj] = f2bf(hv - bf2f(hh[jj]));
        }
        *(f32x4*)&c[(size_t)grow * H_SZ + jg] = cv;
        ushort* hd = hdest + (size_t)grow * ldh + jg;
        uint hv2[2], lv2[2];
        hv2[0] = (uint)hh[0] | ((uint)hh[1] << 16);
        hv2[1] = (uint)hh[2] | ((uint)hh[3] << 16);
        lv2[0] = (uint)hl[0] | ((uint)hl[1] << 16);
        lv2[1] = (uint)hl[2] | ((uint)hl[3] << 16);
        *(uint*)&hd[0] = hv2[0];
        *(uint*)&hd[2] = hv2[1];
        *(uint*)&hd[1024] = lv2[0];
        *(uint*)&hd[1026] = lv2[1];            // h_lo always hi_base + 1024

        if (xdest) {                            // fused x_{t+1} conversion
            const int idx = flat * 256 + tid;   // exactly B*I = 131072
            const int b = idx >> 8, i = idx & 255;
            const float v = xsrc[(size_t)b * (T_SZ * I_SZ) + i];
            const ushort hi = f2bf(v), lo = f2bf(v - bf2f(hi));
            xdest[(size_t)b * APE + i] = hi;
            xdest[(size_t)b * APE + 256 + i] = lo;
        }
    } else {
#pragma unroll
        for (int m = 0; m < 2; ++m)
#pragma unroll
            for (int n = 0; n < 2; ++n) {
                const int col = n0 + wn * 32 + n * 16 + l15;
                const float bv = bias[col];
#pragma unroll
                for (int r = 0; r < 4; ++r) {
                    const int row = m0 + wm * 32 + m * 16 + lq * 4 + r;
                    out[(size_t)row * ldo + col] = acc[m][n][r] + bv;
                }
            }
    }
}

// ---------------------------------------------------------------------------
// Row argmax (first-occurrence) + embedding gather into next dec A's xc.
// ---------------------------------------------------------------------------
__global__ __launch_bounds__(256) void argmax_embed(
    const float* __restrict__ logits, int ldl,
    const float* __restrict__ embed_W,
    ushort* __restrict__ xdest)
{
    const int b = blockIdx.x;
    const float* row = logits + (size_t)b * ldl;
    const int tid = threadIdx.x;
    float best = -INFINITY;
    int bi = V_SZ;
#pragma unroll
    for (int v = tid; v < V_SZ; v += 256) {
        const float x = row[v];
        if (x > best) { best = x; bi = v; }
    }
    __shared__ float sv[256];
    __shared__ int si[256];
    sv[tid] = best; si[tid] = bi;
    __syncthreads();
    for (int s = 128; s > 0; s >>= 1) {
        if (tid < s) {
            const float ov = sv[tid + s]; const int oi = si[tid + s];
            if (ov > sv[tid] || (ov == sv[tid] && oi < si[tid])) { sv[tid] = ov; si[tid] = oi; }
        }
        __syncthreads();
    }
    if (tid < E_SZ) {
        const int yb = si[0];
        const float v = embed_W[(size_t)yb * E_SZ + tid];
        const ushort hi = f2bf(v), lo = f2bf(v - bf2f(hi));
        ushort* xd = xdest + (size_t)b * APD;
        xd[tid] = hi;
        xd[8 + tid] = hi;
        xd[16 + tid] = lo;
    }
}

// ---------------------------------------------------------------------------
// Weight packing (gate-permuted rows n' = jhi*64 + g*16 + jlo).
// ---------------------------------------------------------------------------
__global__ void pack_enc(const float* __restrict__ Wih, const float* __restrict__ Whh,
                         const float* __restrict__ b, ushort* __restrict__ Wp,
                         float* __restrict__ bp)
{
    const int k = blockIdx.x * 256 + threadIdx.x;   // < 3840
    const int np = blockIdx.y;                      // < 4096
    const int orig = ((np >> 4) & 3) * H_SZ + (np >> 6) * 16 + (np & 15);
    float v; bool lo = false;
    if (k < 256)        v = Wih[(size_t)orig * I_SZ + k];
    else if (k < 512) { v = Wih[(size_t)orig * I_SZ + k - 256]; lo = true; }
    else if (k < 768)   v = Wih[(size_t)orig * I_SZ + k - 512];
    else if (k < 1792)  v = Whh[(size_t)orig * H_SZ + k - 768];
    else if (k < 2816) { v = Whh[(size_t)orig * H_SZ + k - 1792]; lo = true; }
    else                v = Whh[(size_t)orig * H_SZ + k - 2816];
    const ushort hi = f2bf(v);
    Wp[(size_t)np * KVE + k] = lo ? f2bf(v - bf2f(hi)) : hi;
    if (k == 0) bp[np] = b[orig];
}

__global__ void pack_dec(const float* __restrict__ Wih, const float* __restrict__ Whh,
                         const float* __restrict__ b, ushort* __restrict__ Wp,
                         float* __restrict__ bp)
{
    const int k = blockIdx.x * 256 + threadIdx.x;   // < 3328 (13*256 exact)
    const int np = blockIdx.y;
    const int orig = ((np >> 4) & 3) * H_SZ + (np >> 6) * 16 + (np & 15);
    float v = 0.f; bool lo = false; bool zero = false;
    if (k < 8)            v = Wih[(size_t)orig * E_SZ + k];
    else if (k < 16)    { v = Wih[(size_t)orig * E_SZ + k - 8]; lo = true; }
    else if (k < 24)      v = Wih[(size_t)orig * E_SZ + k - 16];
    else if (k < 128)     zero = true;
    else if (k < 1152)    v = Whh[(size_t)orig * H_SZ + k - 128];
    else if (k < 2176)  { v = Whh[(size_t)orig * H_SZ + k - 1152]; lo = true; }
    else if (k < 3200)    v = Whh[(size_t)orig * H_SZ + k - 2176];
    else                  zero = true;
    ushort w = 0;
    if (!zero) { const ushort hi = f2bf(v); w = lo ? f2bf(v - bf2f(hi)) : hi; }
    Wp[(size_t)np * KVD + k] = w;
    if (k == 0) bp[np] = b[orig];
}

__global__ void pack_fc(const float* __restrict__ W, ushort* __restrict__ Wp)
{
    const int k = blockIdx.x * 256 + threadIdx.x;   // < 3072
    const int np = blockIdx.y;                      // < 1024 (no permute)
    float v; bool lo = false;
    if (k < 1024)       v = W[(size_t)np * H_SZ + k];
    else if (k < 2048) { v = W[(size_t)np * H_SZ + k - 1024]; lo = true; }
    else                v = W[(size_t)np * H_SZ + k - 2048];
    const ushort hi = f2bf(v);
    Wp[(size_t)np * KVF + k] = lo ? f2bf(v - bf2f(hi)) : hi;
}

// ---------------------------------------------------------------------------
// Init: zero c + A_enc0 h region; convert x(0); xc(0) from embed row 0;
// zero dec xc pads (both buffers).
// ---------------------------------------------------------------------------
__global__ void init_all(const float* __restrict__ x0,
                         const float* __restrict__ embed_W,
                         float* __restrict__ c,
                         ushort* __restrict__ Aenc0,
                         ushort* __restrict__ Adec0,
                         ushort* __restrict__ Adec1)
{
    const int idx = blockIdx.x * 256 + threadIdx.x;   // < 512*2048
    {
        const int b = idx >> 11, k = idx & 2047;
        Aenc0[(size_t)b * APE + 512 + k] = 0;
    }
    if (idx < B_SZ * H_SZ) c[idx] = 0.f;
    if (idx < B_SZ * I_SZ) {
        const int b = idx >> 8, i = idx & 255;
        const float v = x0[(size_t)b * (T_SZ * I_SZ) + i];
        const ushort hi = f2bf(v), lo = f2bf(v - bf2f(hi));
        Aenc0[(size_t)b * APE + i] = hi;
        Aenc0[(size_t)b * APE + 256 + i] = lo;
    }
    if (idx < B_SZ * 104) {
        const int b = idx / 104, col = 24 + idx % 104;
        Adec0[(size_t)b * APD + col] = 0;
        Adec1[(size_t)b * APD + col] = 0;
    }
    if (idx < B_SZ * 24) {
        const int b = idx / 24, col = idx % 24;
        float v;
        if (col < 8)       v = embed_W[col];
        else if (col < 16) v = embed_W[col - 8];
        else               v = embed_W[col - 16];
        const ushort hi = f2bf(v);
        Adec0[(size_t)b * APD + col] = (col < 16) ? hi : f2bf(v - bf2f(hi));
    }
}

extern "C" void kernel_launch(void* const* d_in, const int* in_sizes, int n_in,
                              void* d_out, int out_size, void* d_ws, size_t ws_size,
                              hipStream_t stream)
{
    const float* x_hist  = (const float*)d_in[0];
    const float* enc_Wih = (const float*)d_in[1];
    const float* enc_Whh = (const float*)d_in[2];
    const float* enc_b   = (const float*)d_in[3];
    const float* embed_W = (const float*)d_in[4];
    const float* dec_Wih = (const float*)d_in[5];
    const float* dec_Whh = (const float*)d_in[6];
    const float* dec_b   = (const float*)d_in[7];
    const float* fc_W    = (const float*)d_in[8];
    const float* fc_b    = (const float*)d_in[9];
    float* out = (float*)d_out;

    char* p = (char*)d_ws;
    auto alloc = [&](size_t bytes) {
        char* r = p;
        p += (bytes + 255) & ~(size_t)255;
        return r;
    };
    ushort* W_enc  = (ushort*)alloc((size_t)4096 * KVE * 2);   // 30 MB
    ushort* W_dec  = (ushort*)alloc((size_t)4096 * KVD * 2);   // 26 MB
    ushort* W_fc   = (ushort*)alloc((size_t)1024 * KVF * 2);   // 6 MB
    ushort* A_enc0 = (ushort*)alloc((size_t)B_SZ * APE * 2);   // 2.5 MB
    ushort* A_enc1 = (ushort*)alloc((size_t)B_SZ * APE * 2);
    ushort* A_dec0 = (ushort*)alloc((size_t)B_SZ * APD * 2);   // 2.13 MB
    ushort* A_dec1 = (ushort*)alloc((size_t)B_SZ * APD * 2);
    float*  cbuf   = (float*)alloc((size_t)B_SZ * H_SZ * 4);   // 2 MB
    float*  bpe    = (float*)alloc(4096 * 4);
    float*  bpd    = (float*)alloc(4096 * 4);

    const dim3 blk(256);
    hipLaunchKernelGGL(pack_enc, dim3(15, 4096), blk, 0, stream, enc_Wih, enc_Whh, enc_b, W_enc, bpe);
    hipLaunchKernelGGL(pack_dec, dim3(13, 4096), blk, 0, stream, dec_Wih, dec_Whh, dec_b, W_dec, bpd);
    hipLaunchKernelGGL(pack_fc,  dim3(12, 1024), blk, 0, stream, fc_W, W_fc);
    hipLaunchKernelGGL(init_all, dim3(4096), blk, 0, stream, x_hist, embed_W, cbuf, A_enc0, A_dec0, A_dec1);

    ushort* Ae[2] = {A_enc0, A_enc1};
    ushort* Ad[2] = {A_dec0, A_dec1};

    // Encoder: A-map offsets per k-tile(64): [0,4):0 [4,28):-256 [28,60):-1280
    for (int t = 0; t < T_SZ; ++t) {
        ushort* hdst; int ldh; const float* xs; ushort* xd;
        if (t < T_SZ - 1) {
            hdst = Ae[(t + 1) & 1] + 512; ldh = APE;
            xs = x_hist + (size_t)(t + 1) * I_SZ;
            xd = Ae[(t + 1) & 1];
        } else {
            hdst = Ad[0] + 128; ldh = APD;
            xs = nullptr; xd = nullptr;
        }
        hipLaunchKernelGGL((gemm_step<8, 60, 4, 28, 0, -256, -1280, true>),
                           dim3(512), blk, 0, stream,
                           Ae[t & 1], APE, W_enc, KVE, bpe, cbuf,
                           hdst, ldh, xs, xd, (float*)nullptr, 0);
    }

    // Decoder: dec map: [0,18):0 [18,50):-1024 [50,52):-3200 (zero-pad tiles)
    // fc map:  [0,16):+128 [16,48):-896
    for (int t = 0; t < FUT; ++t) {
        hipLaunchKernelGGL((gemm_step<8, 52, 18, 50, 0, -1024, -3200, true>),
                           dim3(512), blk, 0, stream,
                           Ad[t & 1], APD, W_dec, KVD, bpd, cbuf,
                           Ad[(t + 1) & 1] + 128, APD,
                           (const float*)nullptr, (ushort*)nullptr,
                           (float*)nullptr, 0);
        float* logits = out + (size_t)t * V_SZ;   // [B, FUT, V]
        hipLaunchKernelGGL((gemm_step<2, 48, 16, 48, 128, -896, -896, false>),
                           dim3(128), blk, 0, stream,
                           Ad[(t + 1) & 1], APD, W_fc, KVF, fc_b,
                           (float*)nullptr, (ushort*)nullptr, 0,
                           (const float*)nullptr, (ushort*)nullptr,
                           logits, FUT * V_SZ);
        hipLaunchKernelGGL(argmax_embed, dim3(512), blk, 0, stream,
                           logits, FUT * V_SZ, embed_W, Ad[(t + 1) & 1]);
    }
}

// Round 10
// 10209.004 us; speedup vs baseline: 1.0201x; 1.0201x over previous
//
#include <hip/hip_runtime.h>
#include <cmath>

typedef __attribute__((ext_vector_type(8))) short short8;
typedef __attribute__((ext_vector_type(4))) float f32x4;

#define B_SZ 512
#define T_SZ 256
#define I_SZ 256
#define H_SZ 1024
#define V_SZ 1024
#define E_SZ 8
#define FUT 64

// R5 numerics (3-product split-bf16). Physical A / virtual W layouts:
// enc A phys: [x_hi 256 | x_lo 256 | h_hi 1024 | h_lo 1024]          = 2560
// dec A phys: [xc 128 (hi8|hi8|lo8|0) | h_hi 1024 | h_lo 1024]       = 2176
// W_enc virt: [Wih_hi|Wih_lo|Wih_hi | Whh_hi|Whh_lo|Whh_hi]          = 3840
// W_dec virt: [Wxc 128 | Whh_hi|Whh_lo|Whh_hi | 0-pad 128]           = 3328
//             (pad tiles never visited: NK=50)
// W_fc  virt: [Wfc_hi | Wfc_lo | Wfc_hi]                             = 3072
#define KVE 3840
#define KVD 3328
#define KVF 3072
#define APE 2560
#define APD 2176

static __device__ __forceinline__ ushort f2bf(float v) {
    uint32_t u = __float_as_uint(v);
    uint32_t r = (u + 0x7fffu + ((u >> 16) & 1u)) >> 16;
    return (ushort)r;
}
static __device__ __forceinline__ float bf2f(ushort b) {
    return __uint_as_float(((uint32_t)b) << 16);
}

#define GLD16(gp, lp)                                                          \
    __builtin_amdgcn_global_load_lds(                                         \
        (const __attribute__((address_space(1))) void*)(gp),                  \
        (__attribute__((address_space(3))) void*)(lp), 16, 0, 0)

// ---------------------------------------------------------------------------
// Split-bf16 GEMM step. Block tile (MFR*32) x (NFR*32), 4 waves (2m x 2n),
// wave tile (MFR*16) x (NFR*16). BK=64. Both operands staged via
// global_load_lds into 4 rotating buffers; counted-vmcnt pipeline: stage
// k-tile p+3 while computing p; steady wait = vmcnt(2*(MFR+NFR)) -- stage p
// complete, 2 stages in flight; no vmcnt(0) drain inside the loop.
// LDS rows: 64 bf16 = 128B = 8 16B-slots, XOR-swizzled slot^(row&7); global
// source column pre-swizzled, ds_read applies the same XOR (T2, rule #21).
// A's virtual K deduped by piecewise source offset (64-aligned boundaries).
// enc/dec: MFR=NFR=2 (64x64, 64 KB LDS, 2 blocks/CU).
// fc:      MFR=NFR=1 (32x32, 32 KB LDS, 512 blocks = 2/CU on all CUs).
// ---------------------------------------------------------------------------
template<int MFR, int NFR, int NTPX, int NK, int T1, int T2,
         int O0, int O1, int O2, bool GATES>
__global__ __launch_bounds__(256) void gemm_step(
    const ushort* __restrict__ A, int astr,
    const ushort* __restrict__ W, int kv,
    const float* __restrict__ bias,
    float* __restrict__ c,
    ushort* __restrict__ hdest, int ldh,
    const float* __restrict__ xsrc, ushort* __restrict__ xdest,
    float* __restrict__ out, int ldo)
{
    constexpr int ABUF = MFR * 2048;             // ushorts per A buffer
    constexpr int WBUF = NFR * 2048;
    __shared__ __align__(16) ushort lds[4 * (ABUF + WBUF)];

    const int tid = threadIdx.x;
    const int lane = tid & 63;
    const int wid = tid >> 6;
    const int wm = wid >> 1, wn = wid & 1;
    const int l15 = lane & 15, lq = lane >> 4;
    const int l7 = lane & 7, l3 = lane >> 3;

    const int flat = blockIdx.x;
    const int xcd = flat & 7, slot = flat >> 3;
    const int n_tile = xcd * NTPX + (slot % NTPX);
    const int m_tile = slot / NTPX;
    const int m0 = m_tile * (MFR * 32);
    const int n0 = n_tile * (NFR * 32);

    f32x4 acc[MFR][NFR];
#pragma unroll
    for (int m = 0; m < MFR; ++m)
#pragma unroll
        for (int n = 0; n < NFR; ++n) { f32x4 z = {0.f, 0.f, 0.f, 0.f}; acc[m][n] = z; }

    // Stage k-tile p (64 cols of A and W) into buffer bufi.
    auto STAGE = [&](int p, int bufi) {
        const int off = p < T1 ? O0 : (p < T2 ? O1 : O2);
        const int kc = p * 64;
        ushort* ab = &lds[bufi * ABUF];
        ushort* wb = &lds[4 * ABUF + bufi * WBUF];
#pragma unroll
        for (int i = 0; i < MFR; ++i) {
            const int rowg = (i * 4 + wid) * 8;    // 8-row group base
            const int row = rowg + l3;
            GLD16(A + (size_t)(m0 + row) * astr + kc + off + ((l7 ^ l3) * 8),
                  ab + rowg * 64);
        }
#pragma unroll
        for (int i = 0; i < NFR; ++i) {
            const int rowg = (i * 4 + wid) * 8;
            const int row = rowg + l3;
            GLD16(W + (size_t)(n0 + row) * kv + kc + ((l7 ^ l3) * 8),
                  wb + rowg * 64);
        }
    };
    auto COMPUTE = [&](int bufi) {
        const ushort* ab = &lds[bufi * ABUF];
        const ushort* wb = &lds[4 * ABUF + bufi * WBUF];
#pragma unroll
        for (int kk = 0; kk < 2; ++kk) {
            short8 af[MFR], wf[NFR];
#pragma unroll
            for (int m = 0; m < MFR; ++m) {
                const int row = wm * (MFR * 16) + m * 16 + l15;
                af[m] = *(const short8*)
                    &ab[row * 64 + (((kk * 4 + lq) ^ (row & 7)) * 8)];
            }
#pragma unroll
            for (int n = 0; n < NFR; ++n) {
                const int row = wn * (NFR * 16) + n * 16 + l15;
                wf[n] = *(const short8*)
                    &wb[row * 64 + (((kk * 4 + lq) ^ (row & 7)) * 8)];
            }
            __builtin_amdgcn_s_setprio(1);
#pragma unroll
            for (int m = 0; m < MFR; ++m)
#pragma unroll
                for (int n = 0; n < NFR; ++n)
                    acc[m][n] = __builtin_amdgcn_mfma_f32_16x16x32_bf16(
                        af[m], wf[n], acc[m][n], 0, 0, 0);
            __builtin_amdgcn_s_setprio(0);
        }
    };

    // ---- pipelined k-loop (any NK; guards fold at compile time) ----
    STAGE(0, 0);
    if (NK > 1) STAGE(1, 1);
    if (NK > 2) STAGE(2, 2);
#pragma unroll 1
    for (int p0 = 0; p0 < NK; p0 += 4) {
#pragma unroll
        for (int j = 0; j < 4; ++j) {
            const int p = p0 + j;
            if (p < NK) {
                // wait: stage p complete. outstanding after = later stages.
                if (p + 2 < NK) {
                    if constexpr (MFR + NFR == 4)
                        asm volatile("s_waitcnt vmcnt(8)" ::: "memory");
                    else
                        asm volatile("s_waitcnt vmcnt(4)" ::: "memory");
                } else if (p + 1 < NK) {
                    if constexpr (MFR + NFR == 4)
                        asm volatile("s_waitcnt vmcnt(4)" ::: "memory");
                    else
                        asm volatile("s_waitcnt vmcnt(2)" ::: "memory");
                } else {
                    asm volatile("s_waitcnt vmcnt(0)" ::: "memory");
                }
                __builtin_amdgcn_s_barrier();
                if (p + 3 < NK) STAGE(p + 3, (j + 3) & 3);
                COMPUTE(j);
            }
        }
    }

    // --- epilogue ----------------------------------------------------------
    if constexpr (GATES) {
        // MFR == NFR == 2 here (64x64 tile). Exchange acc via LDS z-tile.
        float* zs = (float*)&lds[0];          // 64*65*4 = 16.6 KB <= 64 KB
        __syncthreads();
#pragma unroll
        for (int m = 0; m < MFR; ++m)
#pragma unroll
            for (int n = 0; n < NFR; ++n)
#pragma unroll
                for (int r = 0; r < 4; ++r)
                    zs[(wm * 32 + m * 16 + lq * 4 + r) * 65 +
                       wn * 32 + n * 16 + l15] = acc[m][n][r];
        __syncthreads();

        const int row = tid & 63;
        const int jl0 = (tid >> 6) * 4;
        const int grow = m0 + row;
        const int jg = n_tile * 16 + jl0;
        const f32x4 bi4 = *(const f32x4*)&bias[n0 + jl0];
        const f32x4 bf4 = *(const f32x4*)&bias[n0 + 16 + jl0];
        const f32x4 bg4 = *(const f32x4*)&bias[n0 + 32 + jl0];
        const f32x4 bo4 = *(const f32x4*)&bias[n0 + 48 + jl0];
        f32x4 cv = *(f32x4*)&c[(size_t)grow * H_SZ + jg];
        ushort hh[4], hl[4];
#pragma unroll
        for (int jj = 0; jj < 4; ++jj) {
            const float zi = zs[row * 65 + jl0 + jj] + bi4[jj];
            const float zf = zs[row * 65 + 16 + jl0 + jj] + bf4[jj];
            const float zg = zs[row * 65 + 32 + jl0 + jj] + bg4[jj];
            const float zo = zs[row * 65 + 48 + jl0 + jj] + bo4[jj];
            const float ig = 1.f / (1.f + expf(-zi));
            const float fg = 1.f / (1.f + expf(-zf));
            const float gg = tanhf(zg);
            const float og = 1.f / (1.f + expf(-zo));
            const float cn = fg * cv[jj] + ig * gg;
            cv[jj] = cn;
            const float hv = og * tanhf(cn);
            hh[jj] = f2bf(hv);
            hl[jj] = f2bf(hv - bf2f(hh[jj]));
        }
        *(f32x4*)&c[(size_t)grow * H_SZ + jg] = cv;
        ushort* hd = hdest + (size_t)grow * ldh + jg;
        uint hv2[2], lv2[2];
        hv2[0] = (uint)hh[0] | ((uint)hh[1] << 16);
        hv2[1] = (uint)hh[2] | ((uint)hh[3] << 16);
        lv2[0] = (uint)hl[0] | ((uint)hl[1] << 16);
        lv2[1] = (uint)hl[2] | ((uint)hl[3] << 16);
        *(uint*)&hd[0] = hv2[0];
        *(uint*)&hd[2] = hv2[1];
        *(uint*)&hd[1024] = lv2[0];
        *(uint*)&hd[1026] = lv2[1];            // h_lo always hi_base + 1024

        if (xdest) {                            // fused x_{t+1} conversion
            const int idx = flat * 256 + tid;   // exactly B*I = 131072
            const int b = idx >> 8, i = idx & 255;
            const float v = xsrc[(size_t)b * (T_SZ * I_SZ) + i];
            const ushort hi = f2bf(v), lo = f2bf(v - bf2f(hi));
            xdest[(size_t)b * APE + i] = hi;
            xdest[(size_t)b * APE + 256 + i] = lo;
        }
    } else {
#pragma unroll
        for (int m = 0; m < MFR; ++m)
#pragma unroll
            for (int n = 0; n < NFR; ++n) {
                const int col = n0 + wn * (NFR * 16) + n * 16 + l15;
                const float bv = bias[col];
#pragma unroll
                for (int r = 0; r < 4; ++r) {
                    const int row = m0 + wm * (MFR * 16) + m * 16 + lq * 4 + r;
                    out[(size_t)row * ldo + col] = acc[m][n][r] + bv;
                }
            }
    }
}

// ---------------------------------------------------------------------------
// Row argmax (first-occurrence) + embedding gather into next dec A's xc.
// ---------------------------------------------------------------------------
__global__ __launch_bounds__(256) void argmax_embed(
    const float* __restrict__ logits, int ldl,
    const float* __restrict__ embed_W,
    ushort* __restrict__ xdest)
{
    const int b = blockIdx.x;
    const float* row = logits + (size_t)b * ldl;
    const int tid = threadIdx.x;
    float best = -INFINITY;
    int bi = V_SZ;
#pragma unroll
    for (int v = tid; v < V_SZ; v += 256) {
        const float x = row[v];
        if (x > best) { best = x; bi = v; }
    }
    __shared__ float sv[256];
    __shared__ int si[256];
    sv[tid] = best; si[tid] = bi;
    __syncthreads();
    for (int s = 128; s > 0; s >>= 1) {
        if (tid < s) {
            const float ov = sv[tid + s]; const int oi = si[tid + s];
            if (ov > sv[tid] || (ov == sv[tid] && oi < si[tid])) { sv[tid] = ov; si[tid] = oi; }
        }
        __syncthreads();
    }
    if (tid < E_SZ) {
        const int yb = si[0];
        const float v = embed_W[(size_t)yb * E_SZ + tid];
        const ushort hi = f2bf(v), lo = f2bf(v - bf2f(hi));
        ushort* xd = xdest + (size_t)b * APD;
        xd[tid] = hi;
        xd[8 + tid] = hi;
        xd[16 + tid] = lo;
    }
}

// ---------------------------------------------------------------------------
// Weight packing (gate-permuted rows n' = jhi*64 + g*16 + jlo).
// ---------------------------------------------------------------------------
__global__ void pack_enc(const float* __restrict__ Wih, const float* __restrict__ Whh,
                         const float* __restrict__ b, ushort* __restrict__ Wp,
                         float* __restrict__ bp)
{
    const int k = blockIdx.x * 256 + threadIdx.x;   // < 3840
    const int np = blockIdx.y;                      // < 4096
    const int orig = ((np >> 4) & 3) * H_SZ + (np >> 6) * 16 + (np & 15);
    float v; bool lo = false;
    if (k < 256)        v = Wih[(size_t)orig * I_SZ + k];
    else if (k < 512) { v = Wih[(size_t)orig * I_SZ + k - 256]; lo = true; }
    else if (k < 768)   v = Wih[(size_t)orig * I_SZ + k - 512];
    else if (k < 1792)  v = Whh[(size_t)orig * H_SZ + k - 768];
    else if (k < 2816) { v = Whh[(size_t)orig * H_SZ + k - 1792]; lo = true; }
    else                v = Whh[(size_t)orig * H_SZ + k - 2816];
    const ushort hi = f2bf(v);
    Wp[(size_t)np * KVE + k] = lo ? f2bf(v - bf2f(hi)) : hi;
    if (k == 0) bp[np] = b[orig];
}

__global__ void pack_dec(const float* __restrict__ Wih, const float* __restrict__ Whh,
                         const float* __restrict__ b, ushort* __restrict__ Wp,
                         float* __restrict__ bp)
{
    const int k = blockIdx.x * 256 + threadIdx.x;   // < 3328 (13*256 exact)
    const int np = blockIdx.y;
    const int orig = ((np >> 4) & 3) * H_SZ + (np >> 6) * 16 + (np & 15);
    float v = 0.f; bool lo = false; bool zero = false;
    if (k < 8)            v = Wih[(size_t)orig * E_SZ + k];
    else if (k < 16)    { v = Wih[(size_t)orig * E_SZ + k - 8]; lo = true; }
    else if (k < 24)      v = Wih[(size_t)orig * E_SZ + k - 16];
    else if (k < 128)     zero = true;
    else if (k < 1152)    v = Whh[(size_t)orig * H_SZ + k - 128];
    else if (k < 2176)  { v = Whh[(size_t)orig * H_SZ + k - 1152]; lo = true; }
    else if (k < 3200)    v = Whh[(size_t)orig * H_SZ + k - 2176];
    else                  zero = true;
    ushort w = 0;
    if (!zero) { const ushort hi = f2bf(v); w = lo ? f2bf(v - bf2f(hi)) : hi; }
    Wp[(size_t)np * KVD + k] = w;
    if (k == 0) bp[np] = b[orig];
}

__global__ void pack_fc(const float* __restrict__ W, ushort* __restrict__ Wp)
{
    const int k = blockIdx.x * 256 + threadIdx.x;   // < 3072
    const int np = blockIdx.y;                      // < 1024 (no permute)
    float v; bool lo = false;
    if (k < 1024)       v = W[(size_t)np * H_SZ + k];
    else if (k < 2048) { v = W[(size_t)np * H_SZ + k - 1024]; lo = true; }
    else                v = W[(size_t)np * H_SZ + k - 2048];
    const ushort hi = f2bf(v);
    Wp[(size_t)np * KVF + k] = lo ? f2bf(v - bf2f(hi)) : hi;
}

// ---------------------------------------------------------------------------
// Init: zero c + A_enc0 h region; convert x(0); xc(0) from embed row 0;
// zero dec xc pads (both buffers).
// ---------------------------------------------------------------------------
__global__ void init_all(const float* __restrict__ x0,
                         const float* __restrict__ embed_W,
                         float* __restrict__ c,
                         ushort* __restrict__ Aenc0,
                         ushort* __restrict__ Adec0,
                         ushort* __restrict__ Adec1)
{
    const int idx = blockIdx.x * 256 + threadIdx.x;   // < 512*2048
    {
        const int b = idx >> 11, k = idx & 2047;
        Aenc0[(size_t)b * APE + 512 + k] = 0;
    }
    if (idx < B_SZ * H_SZ) c[idx] = 0.f;
    if (idx < B_SZ * I_SZ) {
        const int b = idx >> 8, i = idx & 255;
        const float v = x0[(size_t)b * (T_SZ * I_SZ) + i];
        const ushort hi = f2bf(v), lo = f2bf(v - bf2f(hi));
        Aenc0[(size_t)b * APE + i] = hi;
        Aenc0[(size_t)b * APE + 256 + i] = lo;
    }
    if (idx < B_SZ * 104) {
        const int b = idx / 104, col = 24 + idx % 104;
        Adec0[(size_t)b * APD + col] = 0;
        Adec1[(size_t)b * APD + col] = 0;
    }
    if (idx < B_SZ * 24) {
        const int b = idx / 24, col = idx % 24;
        float v;
        if (col < 8)       v = embed_W[col];
        else if (col < 16) v = embed_W[col - 8];
        else               v = embed_W[col - 16];
        const ushort hi = f2bf(v);
        Adec0[(size_t)b * APD + col] = (col < 16) ? hi : f2bf(v - bf2f(hi));
    }
}

extern "C" void kernel_launch(void* const* d_in, const int* in_sizes, int n_in,
                              void* d_out, int out_size, void* d_ws, size_t ws_size,
                              hipStream_t stream)
{
    const float* x_hist  = (const float*)d_in[0];
    const float* enc_Wih = (const float*)d_in[1];
    const float* enc_Whh = (const float*)d_in[2];
    const float* enc_b   = (const float*)d_in[3];
    const float* embed_W = (const float*)d_in[4];
    const float* dec_Wih = (const float*)d_in[5];
    const float* dec_Whh = (const float*)d_in[6];
    const float* dec_b   = (const float*)d_in[7];
    const float* fc_W    = (const float*)d_in[8];
    const float* fc_b    = (const float*)d_in[9];
    float* out = (float*)d_out;

    char* p = (char*)d_ws;
    auto alloc = [&](size_t bytes) {
        char* r = p;
        p += (bytes + 255) & ~(size_t)255;
        return r;
    };
    ushort* W_enc  = (ushort*)alloc((size_t)4096 * KVE * 2);   // 30 MB
    ushort* W_dec  = (ushort*)alloc((size_t)4096 * KVD * 2);   // 26 MB
    ushort* W_fc   = (ushort*)alloc((size_t)1024 * KVF * 2);   // 6 MB
    ushort* A_enc0 = (ushort*)alloc((size_t)B_SZ * APE * 2);   // 2.5 MB
    ushort* A_enc1 = (ushort*)alloc((size_t)B_SZ * APE * 2);
    ushort* A_dec0 = (ushort*)alloc((size_t)B_SZ * APD * 2);   // 2.13 MB
    ushort* A_dec1 = (ushort*)alloc((size_t)B_SZ * APD * 2);
    float*  cbuf   = (float*)alloc((size_t)B_SZ * H_SZ * 4);   // 2 MB
    float*  bpe    = (float*)alloc(4096 * 4);
    float*  bpd    = (float*)alloc(4096 * 4);

    const dim3 blk(256);
    hipLaunchKernelGGL(pack_enc, dim3(15, 4096), blk, 0, stream, enc_Wih, enc_Whh, enc_b, W_enc, bpe);
    hipLaunchKernelGGL(pack_dec, dim3(13, 4096), blk, 0, stream, dec_Wih, dec_Whh, dec_b, W_dec, bpd);
    hipLaunchKernelGGL(pack_fc,  dim3(12, 1024), blk, 0, stream, fc_W, W_fc);
    hipLaunchKernelGGL(init_all, dim3(4096), blk, 0, stream, x_hist, embed_W, cbuf, A_enc0, A_dec0, A_dec1);

    ushort* Ae[2] = {A_enc0, A_enc1};
    ushort* Ad[2] = {A_dec0, A_dec1};

    // Encoder: A-map offsets per k-tile(64): [0,4):0 [4,28):-256 [28,60):-1280
    for (int t = 0; t < T_SZ; ++t) {
        ushort* hdst; int ldh; const float* xs; ushort* xd;
        if (t < T_SZ - 1) {
            hdst = Ae[(t + 1) & 1] + 512; ldh = APE;
            xs = x_hist + (size_t)(t + 1) * I_SZ;
            xd = Ae[(t + 1) & 1];
        } else {
            hdst = Ad[0] + 128; ldh = APD;
            xs = nullptr; xd = nullptr;
        }
        hipLaunchKernelGGL((gemm_step<2, 2, 8, 60, 4, 28, 0, -256, -1280, true>),
                           dim3(512), blk, 0, stream,
                           Ae[t & 1], APE, W_enc, KVE, bpe, cbuf,
                           hdst, ldh, xs, xd, (float*)nullptr, 0);
    }

    // Decoder: dec map (NK=50, pad tiles dropped): [0,18):0 [18,50):-1024
    // fc map:  [0,16):+128 [16,48):-896
    for (int t = 0; t < FUT; ++t) {
        hipLaunchKernelGGL((gemm_step<2, 2, 8, 50, 18, 50, 0, -1024, -1024, true>),
                           dim3(512), blk, 0, stream,
                           Ad[t & 1], APD, W_dec, KVD, bpd, cbuf,
                           Ad[(t + 1) & 1] + 128, APD,
                           (const float*)nullptr, (ushort*)nullptr,
                           (float*)nullptr, 0);
        float* logits = out + (size_t)t * V_SZ;   // [B, FUT, V]
        hipLaunchKernelGGL((gemm_step<1, 1, 4, 48, 16, 48, 128, -896, -896, false>),
                           dim3(512), blk, 0, stream,
                           Ad[(t + 1) & 1], APD, W_fc, KVF, fc_b,
                           (float*)nullptr, (ushort*)nullptr, 0,
                           (const float*)nullptr, (ushort*)nullptr,
                           logits, FUT * V_SZ);
        hipLaunchKernelGGL(argmax_embed, dim3(512), blk, 0, stream,
                           logits, FUT * V_SZ, embed_W, Ad[(t + 1) & 1]);
    }
}

// Round 11
// 10017.587 us; speedup vs baseline: 1.0396x; 1.0191x over previous
//
#include <hip/hip_runtime.h>
#include <cmath>

typedef __attribute__((ext_vector_type(8))) short short8;
typedef __attribute__((ext_vector_type(4))) float f32x4;

#define B_SZ 512
#define T_SZ 256
#define I_SZ 256
#define H_SZ 1024
#define V_SZ 1024
#define E_SZ 8
#define FUT 64

// R5 numerics (3-product split-bf16). Physical A / virtual W layouts:
// enc A phys: [x_hi 256 | x_lo 256 | h_hi 1024 | h_lo 1024]          = 2560
// dec A phys: [xc 128 (hi8|hi8|lo8|0) | h_hi 1024 | h_lo 1024]       = 2176
// W_enc virt: [Wih_hi|Wih_lo|Wih_hi | Whh_hi|Whh_lo|Whh_hi]          = 3840
// W_dec virt: [Wxc 128 | Whh_hi|Whh_lo|Whh_hi | 0-pad 128]  (NK=50)  = 3328
// W_fc  virt: [Wfc_hi | Wfc_lo | Wfc_hi]                             = 3072
#define KVE 3840
#define KVD 3328
#define KVF 3072
#define APE 2560
#define APD 2176

static __device__ __forceinline__ ushort f2bf(float v) {
    uint32_t u = __float_as_uint(v);
    uint32_t r = (u + 0x7fffu + ((u >> 16) & 1u)) >> 16;
    return (ushort)r;
}
static __device__ __forceinline__ float bf2f(ushort b) {
    return __uint_as_float(((uint32_t)b) << 16);
}
// Monotone float->uint mapping: a > b  <=>  map(a) > map(b) (finite floats).
static __device__ __forceinline__ uint32_t fmono(float f) {
    uint32_t u = __float_as_uint(f);
    return (u & 0x80000000u) ? ~u : (u | 0x80000000u);
}

#define GLD16(gp, lp)                                                          \
    __builtin_amdgcn_global_load_lds(                                         \
        (const __attribute__((address_space(1))) void*)(gp),                  \
        (__attribute__((address_space(3))) void*)(lp), 16, 0, 0)

// ---------------------------------------------------------------------------
// Split-bf16 GEMM step. Block tile (MFR*32) x (NFR*32), 4 waves (2m x 2n),
// wave tile (MFR*16) x (NFR*16). BK=64. Both operands staged via
// global_load_lds into 4 rotating buffers; counted-vmcnt pipeline: stage
// k-tile p+3 while computing p; steady wait = vmcnt(2*(MFR+NFR)) -- stage p
// complete, 2 stages in flight; no vmcnt(0) drain inside the loop.
// LDS rows: 64 bf16 = 128B = 8 16B-slots, XOR-swizzled slot^(row&7); global
// source column pre-swizzled, ds_read applies the same XOR (T2, rule #21).
// A's virtual K deduped by piecewise source offset (64-aligned boundaries).
// enc/dec: MFR=NFR=2 (64x64, 64 KB LDS, 2 blocks/CU), GATES=true.
// fc:      MFR=NFR=1 (32x32), GATES=false, + fused per-row argmax via
//          packed-key atomicMax (keys != nullptr).
// ---------------------------------------------------------------------------
template<int MFR, int NFR, int NTPX, int NK, int T1, int T2,
         int O0, int O1, int O2, bool GATES>
__global__ __launch_bounds__(256) void gemm_step(
    const ushort* __restrict__ A, int astr,
    const ushort* __restrict__ W, int kv,
    const float* __restrict__ bias,
    float* __restrict__ c,
    ushort* __restrict__ hdest, int ldh,
    const float* __restrict__ xsrc, ushort* __restrict__ xdest,
    float* __restrict__ out, int ldo,
    unsigned long long* __restrict__ keys)
{
    constexpr int ABUF = MFR * 2048;             // ushorts per A buffer
    constexpr int WBUF = NFR * 2048;
    __shared__ __align__(16) ushort lds[4 * (ABUF + WBUF)];

    const int tid = threadIdx.x;
    const int lane = tid & 63;
    const int wid = tid >> 6;
    const int wm = wid >> 1, wn = wid & 1;
    const int l15 = lane & 15, lq = lane >> 4;
    const int l7 = lane & 7, l3 = lane >> 3;

    const int flat = blockIdx.x;
    const int xcd = flat & 7, slot = flat >> 3;
    const int n_tile = xcd * NTPX + (slot % NTPX);
    const int m_tile = slot / NTPX;
    const int m0 = m_tile * (MFR * 32);
    const int n0 = n_tile * (NFR * 32);

    f32x4 acc[MFR][NFR];
#pragma unroll
    for (int m = 0; m < MFR; ++m)
#pragma unroll
        for (int n = 0; n < NFR; ++n) { f32x4 z = {0.f, 0.f, 0.f, 0.f}; acc[m][n] = z; }

    // Stage k-tile p (64 cols of A and W) into buffer bufi.
    auto STAGE = [&](int p, int bufi) {
        const int off = p < T1 ? O0 : (p < T2 ? O1 : O2);
        const int kc = p * 64;
        ushort* ab = &lds[bufi * ABUF];
        ushort* wb = &lds[4 * ABUF + bufi * WBUF];
#pragma unroll
        for (int i = 0; i < MFR; ++i) {
            const int rowg = (i * 4 + wid) * 8;    // 8-row group base
            const int row = rowg + l3;
            GLD16(A + (size_t)(m0 + row) * astr + kc + off + ((l7 ^ l3) * 8),
                  ab + rowg * 64);
        }
#pragma unroll
        for (int i = 0; i < NFR; ++i) {
            const int rowg = (i * 4 + wid) * 8;
            const int row = rowg + l3;
            GLD16(W + (size_t)(n0 + row) * kv + kc + ((l7 ^ l3) * 8),
                  wb + rowg * 64);
        }
    };
    auto COMPUTE = [&](int bufi) {
        const ushort* ab = &lds[bufi * ABUF];
        const ushort* wb = &lds[4 * ABUF + bufi * WBUF];
#pragma unroll
        for (int kk = 0; kk < 2; ++kk) {
            short8 af[MFR], wf[NFR];
#pragma unroll
            for (int m = 0; m < MFR; ++m) {
                const int row = wm * (MFR * 16) + m * 16 + l15;
                af[m] = *(const short8*)
                    &ab[row * 64 + (((kk * 4 + lq) ^ (row & 7)) * 8)];
            }
#pragma unroll
            for (int n = 0; n < NFR; ++n) {
                const int row = wn * (NFR * 16) + n * 16 + l15;
                wf[n] = *(const short8*)
                    &wb[row * 64 + (((kk * 4 + lq) ^ (row & 7)) * 8)];
            }
#pragma unroll
            for (int m = 0; m < MFR; ++m)
#pragma unroll
                for (int n = 0; n < NFR; ++n)
                    acc[m][n] = __builtin_amdgcn_mfma_f32_16x16x32_bf16(
                        af[m], wf[n], acc[m][n], 0, 0, 0);
        }
    };

    // ---- pipelined k-loop (any NK; guards fold at compile time) ----
    STAGE(0, 0);
    if (NK > 1) STAGE(1, 1);
    if (NK > 2) STAGE(2, 2);
#pragma unroll 1
    for (int p0 = 0; p0 < NK; p0 += 4) {
#pragma unroll
        for (int j = 0; j < 4; ++j) {
            const int p = p0 + j;
            if (p < NK) {
                // wait: stage p complete. outstanding after = later stages.
                if (p + 2 < NK) {
                    if constexpr (MFR + NFR == 4)
                        asm volatile("s_waitcnt vmcnt(8)" ::: "memory");
                    else
                        asm volatile("s_waitcnt vmcnt(4)" ::: "memory");
                } else if (p + 1 < NK) {
                    if constexpr (MFR + NFR == 4)
                        asm volatile("s_waitcnt vmcnt(4)" ::: "memory");
                    else
                        asm volatile("s_waitcnt vmcnt(2)" ::: "memory");
                } else {
                    asm volatile("s_waitcnt vmcnt(0)" ::: "memory");
                }
                __builtin_amdgcn_s_barrier();
                if (p + 3 < NK) STAGE(p + 3, (j + 3) & 3);
                COMPUTE(j);
            }
        }
    }

    // --- epilogue ----------------------------------------------------------
    if constexpr (GATES) {
        // MFR == NFR == 2 here (64x64 tile). Exchange acc via LDS z-tile.
        float* zs = (float*)&lds[0];          // 64*65*4 = 16.6 KB <= 64 KB
        __syncthreads();
#pragma unroll
        for (int m = 0; m < MFR; ++m)
#pragma unroll
            for (int n = 0; n < NFR; ++n)
#pragma unroll
                for (int r = 0; r < 4; ++r)
                    zs[(wm * 32 + m * 16 + lq * 4 + r) * 65 +
                       wn * 32 + n * 16 + l15] = acc[m][n][r];
        __syncthreads();

        const int row = tid & 63;
        const int jl0 = (tid >> 6) * 4;
        const int grow = m0 + row;
        const int jg = n_tile * 16 + jl0;
        const f32x4 bi4 = *(const f32x4*)&bias[n0 + jl0];
        const f32x4 bf4 = *(const f32x4*)&bias[n0 + 16 + jl0];
        const f32x4 bg4 = *(const f32x4*)&bias[n0 + 32 + jl0];
        const f32x4 bo4 = *(const f32x4*)&bias[n0 + 48 + jl0];
        f32x4 cv = *(f32x4*)&c[(size_t)grow * H_SZ + jg];
        ushort hh[4], hl[4];
#pragma unroll
        for (int jj = 0; jj < 4; ++jj) {
            const float zi = zs[row * 65 + jl0 + jj] + bi4[jj];
            const float zf = zs[row * 65 + 16 + jl0 + jj] + bf4[jj];
            const float zg = zs[row * 65 + 32 + jl0 + jj] + bg4[jj];
            const float zo = zs[row * 65 + 48 + jl0 + jj] + bo4[jj];
            const float ig = 1.f / (1.f + expf(-zi));
            const float fg = 1.f / (1.f + expf(-zf));
            const float gg = tanhf(zg);
            const float og = 1.f / (1.f + expf(-zo));
            const float cn = fg * cv[jj] + ig * gg;
            cv[jj] = cn;
            const float hv = og * tanhf(cn);
            hh[jj] = f2bf(hv);
            hl[jj] = f2bf(hv - bf2f(hh[jj]));
        }
        *(f32x4*)&c[(size_t)grow * H_SZ + jg] = cv;
        ushort* hd = hdest + (size_t)grow * ldh + jg;
        uint hv2[2], lv2[2];
        hv2[0] = (uint)hh[0] | ((uint)hh[1] << 16);
        hv2[1] = (uint)hh[2] | ((uint)hh[3] << 16);
        lv2[0] = (uint)hl[0] | ((uint)hl[1] << 16);
        lv2[1] = (uint)hl[2] | ((uint)hl[3] << 16);
        *(uint*)&hd[0] = hv2[0];
        *(uint*)&hd[2] = hv2[1];
        *(uint*)&hd[1024] = lv2[0];
        *(uint*)&hd[1026] = lv2[1];            // h_lo always hi_base + 1024

        if (xdest) {                            // fused x_{t+1} conversion
            const int idx = flat * 256 + tid;   // exactly B*I = 131072
            const int b = idx >> 8, i = idx & 255;
            const float v = xsrc[(size_t)b * (T_SZ * I_SZ) + i];
            const ushort hi = f2bf(v), lo = f2bf(v - bf2f(hi));
            xdest[(size_t)b * APE + i] = hi;
            xdest[(size_t)b * APE + 256 + i] = lo;
        }
    } else {
        // MFR == NFR == 1 (32x32). Store logits; fused per-row argmax.
        float vals[4];
        const int col = n0 + wn * 16 + l15;
        const float bv = bias[col];
#pragma unroll
        for (int r = 0; r < 4; ++r) {
            const int row = m0 + wm * 16 + lq * 4 + r;
            vals[r] = acc[0][0][r] + bv;
            out[(size_t)row * ldo + col] = vals[r];
        }
        if (keys) {
            float* zs = (float*)&lds[0];        // 32*33*4 = 4.2 KB
            __syncthreads();
#pragma unroll
            for (int r = 0; r < 4; ++r)
                zs[(wm * 16 + lq * 4 + r) * 33 + wn * 16 + l15] = vals[r];
            __syncthreads();
            if (tid < 32) {
                const int row = tid;
                float best = zs[row * 33];
                int bc = 0;
#pragma unroll
                for (int cc = 1; cc < 32; ++cc) {
                    const float x = zs[row * 33 + cc];
                    if (x > best) { best = x; bc = cc; }   // strict > : earliest col
                }
                const unsigned long long key =
                    ((unsigned long long)fmono(best) << 32) |
                    (unsigned long long)(V_SZ - 1 - (n0 + bc));
                atomicMax(&keys[m0 + row], key);
            }
        }
    }
}

// ---------------------------------------------------------------------------
// Gather: read per-row argmax key -> embed row -> xc of next dec A buffer;
// reset key to 0 for the next step (same-wave read-before-write).
// Grid 16 x 256, idx = b*8 + e (8 lanes per b, same wave).
// ---------------------------------------------------------------------------
__global__ __launch_bounds__(256) void gather_embed(
    unsigned long long* __restrict__ keys,
    const float* __restrict__ embed_W,
    ushort* __restrict__ xdest)
{
    const int idx = blockIdx.x * 256 + threadIdx.x;   // < 4096
    const int b = idx >> 3, e = idx & 7;
    const unsigned long long key = keys[b];
    const int yb = V_SZ - 1 - (int)(key & 0xffffffffu);
    const float v = embed_W[(size_t)yb * E_SZ + e];
    const ushort hi = f2bf(v), lo = f2bf(v - bf2f(hi));
    ushort* xd = xdest + (size_t)b * APD;
    xd[e] = hi;
    xd[8 + e] = hi;
    xd[16 + e] = lo;
    if (e == 0) keys[b] = 0ull;                 // after the wave's reads
}

// ---------------------------------------------------------------------------
// Weight packing (gate-permuted rows n' = jhi*64 + g*16 + jlo).
// ---------------------------------------------------------------------------
__global__ void pack_enc(const float* __restrict__ Wih, const float* __restrict__ Whh,
                         const float* __restrict__ b, ushort* __restrict__ Wp,
                         float* __restrict__ bp)
{
    const int k = blockIdx.x * 256 + threadIdx.x;   // < 3840
    const int np = blockIdx.y;                      // < 4096
    const int orig = ((np >> 4) & 3) * H_SZ + (np >> 6) * 16 + (np & 15);
    float v; bool lo = false;
    if (k < 256)        v = Wih[(size_t)orig * I_SZ + k];
    else if (k < 512) { v = Wih[(size_t)orig * I_SZ + k - 256]; lo = true; }
    else if (k < 768)   v = Wih[(size_t)orig * I_SZ + k - 512];
    else if (k < 1792)  v = Whh[(size_t)orig * H_SZ + k - 768];
    else if (k < 2816) { v = Whh[(size_t)orig * H_SZ + k - 1792]; lo = true; }
    else                v = Whh[(size_t)orig * H_SZ + k - 2816];
    const ushort hi = f2bf(v);
    Wp[(size_t)np * KVE + k] = lo ? f2bf(v - bf2f(hi)) : hi;
    if (k == 0) bp[np] = b[orig];
}

__global__ void pack_dec(const float* __restrict__ Wih, const float* __restrict__ Whh,
                         const float* __restrict__ b, ushort* __restrict__ Wp,
                         float* __restrict__ bp)
{
    const int k = blockIdx.x * 256 + threadIdx.x;   // < 3328 (13*256 exact)
    const int np = blockIdx.y;
    const int orig = ((np >> 4) & 3) * H_SZ + (np >> 6) * 16 + (np & 15);
    float v = 0.f; bool lo = false; bool zero = false;
    if (k < 8)            v = Wih[(size_t)orig * E_SZ + k];
    else if (k < 16)    { v = Wih[(size_t)orig * E_SZ + k - 8]; lo = true; }
    else if (k < 24)      v = Wih[(size_t)orig * E_SZ + k - 16];
    else if (k < 128)     zero = true;
    else if (k < 1152)    v = Whh[(size_t)orig * H_SZ + k - 128];
    else if (k < 2176)  { v = Whh[(size_t)orig * H_SZ + k - 1152]; lo = true; }
    else if (k < 3200)    v = Whh[(size_t)orig * H_SZ + k - 2176];
    else                  zero = true;
    ushort w = 0;
    if (!zero) { const ushort hi = f2bf(v); w = lo ? f2bf(v - bf2f(hi)) : hi; }
    Wp[(size_t)np * KVD + k] = w;
    if (k == 0) bp[np] = b[orig];
}

__global__ void pack_fc(const float* __restrict__ W, ushort* __restrict__ Wp)
{
    const int k = blockIdx.x * 256 + threadIdx.x;   // < 3072
    const int np = blockIdx.y;                      // < 1024 (no permute)
    float v; bool lo = false;
    if (k < 1024)       v = W[(size_t)np * H_SZ + k];
    else if (k < 2048) { v = W[(size_t)np * H_SZ + k - 1024]; lo = true; }
    else                v = W[(size_t)np * H_SZ + k - 2048];
    const ushort hi = f2bf(v);
    Wp[(size_t)np * KVF + k] = lo ? f2bf(v - bf2f(hi)) : hi;
}

// ---------------------------------------------------------------------------
// Init: zero c + A_enc0 h region; convert x(0); xc(0) from embed row 0;
// zero dec xc pads (both buffers); zero argmax keys.
// ---------------------------------------------------------------------------
__global__ void init_all(const float* __restrict__ x0,
                         const float* __restrict__ embed_W,
                         float* __restrict__ c,
                         ushort* __restrict__ Aenc0,
                         ushort* __restrict__ Adec0,
                         ushort* __restrict__ Adec1,
                         unsigned long long* __restrict__ keys)
{
    const int idx = blockIdx.x * 256 + threadIdx.x;   // < 512*2048
    {
        const int b = idx >> 11, k = idx & 2047;
        Aenc0[(size_t)b * APE + 512 + k] = 0;
    }
    if (idx < B_SZ * H_SZ) c[idx] = 0.f;
    if (idx < B_SZ) keys[idx] = 0ull;
    if (idx < B_SZ * I_SZ) {
        const int b = idx >> 8, i = idx & 255;
        const float v = x0[(size_t)b * (T_SZ * I_SZ) + i];
        const ushort hi = f2bf(v), lo = f2bf(v - bf2f(hi));
        Aenc0[(size_t)b * APE + i] = hi;
        Aenc0[(size_t)b * APE + 256 + i] = lo;
    }
    if (idx < B_SZ * 104) {
        const int b = idx / 104, col = 24 + idx % 104;
        Adec0[(size_t)b * APD + col] = 0;
        Adec1[(size_t)b * APD + col] = 0;
    }
    if (idx < B_SZ * 24) {
        const int b = idx / 24, col = idx % 24;
        float v;
        if (col < 8)       v = embed_W[col];
        else if (col < 16) v = embed_W[col - 8];
        else               v = embed_W[col - 16];
        const ushort hi = f2bf(v);
        Adec0[(size_t)b * APD + col] = (col < 16) ? hi : f2bf(v - bf2f(hi));
    }
}

extern "C" void kernel_launch(void* const* d_in, const int* in_sizes, int n_in,
                              void* d_out, int out_size, void* d_ws, size_t ws_size,
                              hipStream_t stream)
{
    const float* x_hist  = (const float*)d_in[0];
    const float* enc_Wih = (const float*)d_in[1];
    const float* enc_Whh = (const float*)d_in[2];
    const float* enc_b   = (const float*)d_in[3];
    const float* embed_W = (const float*)d_in[4];
    const float* dec_Wih = (const float*)d_in[5];
    const float* dec_Whh = (const float*)d_in[6];
    const float* dec_b   = (const float*)d_in[7];
    const float* fc_W    = (const float*)d_in[8];
    const float* fc_b    = (const float*)d_in[9];
    float* out = (float*)d_out;

    char* p = (char*)d_ws;
    auto alloc = [&](size_t bytes) {
        char* r = p;
        p += (bytes + 255) & ~(size_t)255;
        return r;
    };
    ushort* W_enc  = (ushort*)alloc((size_t)4096 * KVE * 2);   // 30 MB
    ushort* W_dec  = (ushort*)alloc((size_t)4096 * KVD * 2);   // 26 MB
    ushort* W_fc   = (ushort*)alloc((size_t)1024 * KVF * 2);   // 6 MB
    ushort* A_enc0 = (ushort*)alloc((size_t)B_SZ * APE * 2);   // 2.5 MB
    ushort* A_enc1 = (ushort*)alloc((size_t)B_SZ * APE * 2);
    ushort* A_dec0 = (ushort*)alloc((size_t)B_SZ * APD * 2);   // 2.13 MB
    ushort* A_dec1 = (ushort*)alloc((size_t)B_SZ * APD * 2);
    float*  cbuf   = (float*)alloc((size_t)B_SZ * H_SZ * 4);   // 2 MB
    float*  bpe    = (float*)alloc(4096 * 4);
    float*  bpd    = (float*)alloc(4096 * 4);
    unsigned long long* keys = (unsigned long long*)alloc(B_SZ * 8);

    const dim3 blk(256);
    hipLaunchKernelGGL(pack_enc, dim3(15, 4096), blk, 0, stream, enc_Wih, enc_Whh, enc_b, W_enc, bpe);
    hipLaunchKernelGGL(pack_dec, dim3(13, 4096), blk, 0, stream, dec_Wih, dec_Whh, dec_b, W_dec, bpd);
    hipLaunchKernelGGL(pack_fc,  dim3(12, 1024), blk, 0, stream, fc_W, W_fc);
    hipLaunchKernelGGL(init_all, dim3(4096), blk, 0, stream, x_hist, embed_W, cbuf, A_enc0, A_dec0, A_dec1, keys);

    ushort* Ae[2] = {A_enc0, A_enc1};
    ushort* Ad[2] = {A_dec0, A_dec1};

    // Encoder: A-map offsets per k-tile(64): [0,4):0 [4,28):-256 [28,60):-1280
    for (int t = 0; t < T_SZ; ++t) {
        ushort* hdst; int ldh; const float* xs; ushort* xd;
        if (t < T_SZ - 1) {
            hdst = Ae[(t + 1) & 1] + 512; ldh = APE;
            xs = x_hist + (size_t)(t + 1) * I_SZ;
            xd = Ae[(t + 1) & 1];
        } else {
            hdst = Ad[0] + 128; ldh = APD;
            xs = nullptr; xd = nullptr;
        }
        hipLaunchKernelGGL((gemm_step<2, 2, 8, 60, 4, 28, 0, -256, -1280, true>),
                           dim3(512), blk, 0, stream,
                           Ae[t & 1], APE, W_enc, KVE, bpe, cbuf,
                           hdst, ldh, xs, xd, (float*)nullptr, 0,
                           (unsigned long long*)nullptr);
    }

    // Decoder: dec map (NK=50, pad tiles dropped): [0,18):0 [18,50):-1024
    // fc map:  [0,16):+128 [16,48):-896
    for (int t = 0; t < FUT; ++t) {
        hipLaunchKernelGGL((gemm_step<2, 2, 8, 50, 18, 50, 0, -1024, -1024, true>),
                           dim3(512), blk, 0, stream,
                           Ad[t & 1], APD, W_dec, KVD, bpd, cbuf,
                           Ad[(t + 1) & 1] + 128, APD,
                           (const float*)nullptr, (ushort*)nullptr,
                           (float*)nullptr, 0,
                           (unsigned long long*)nullptr);
        float* logits = out + (size_t)t * V_SZ;   // [B, FUT, V]
        hipLaunchKernelGGL((gemm_step<1, 1, 4, 48, 16, 48, 128, -896, -896, false>),
                           dim3(512), blk, 0, stream,
                           Ad[(t + 1) & 1], APD, W_fc, KVF, fc_b,
                           (float*)nullptr, (ushort*)nullptr, 0,
                           (const float*)nullptr, (ushort*)nullptr,
                           logits, FUT * V_SZ, keys);
        hipLaunchKernelGGL(gather_embed, dim3(16), blk, 0, stream,
                           keys, embed_W, Ad[(t + 1) & 1]);
    }
}

// Round 12
// 9824.567 us; speedup vs baseline: 1.0601x; 1.0196x over previous
//
#include <hip/hip_runtime.h>
#include <cmath>

typedef __attribute__((ext_vector_type(8))) short short8;
typedef __attribute__((ext_vector_type(4))) float f32x4;

#define B_SZ 512
#define T_SZ 256
#define I_SZ 256
#define H_SZ 1024
#define V_SZ 1024
#define E_SZ 8
#define FUT 64

// R5 numerics (3 products: A_hi*W_hi + A_hi*W_lo + A_lo*W_hi), paired layout:
// A phys (unchanged):
//   enc: [x_hi 256 | x_lo 256 | h_hi 1024 | h_lo 1024] = 2560
//   dec: [xc 128 (x_hi8|x_hi8|x_lo8|0) | h_hi 1024 | h_lo 1024] = 2176
// W packed, two regions:
//   paired: per hi-A-seg p (64 cols): [W_hi(seg p) 64 | W_lo(seg p) 64]
//   single: per lo-A-seg s: [W_hi(seg s) 64]   (+ dec xc pre-expanded tiles)
//   W_enc = 20*128 + 20*64 = 3840 ; W_dec = 16*128 + 18*64 = 3200 ;
//   W_fc  = 16*128 + 16*64 = 3072
#define KVE 3840
#define KVD 3200
#define KVF 3072
#define APE 2560
#define APD 2176

static __device__ __forceinline__ ushort f2bf(float v) {
    uint32_t u = __float_as_uint(v);
    uint32_t r = (u + 0x7fffu + ((u >> 16) & 1u)) >> 16;
    return (ushort)r;
}
static __device__ __forceinline__ float bf2f(ushort b) {
    return __uint_as_float(((uint32_t)b) << 16);
}
// Monotone float->uint mapping: a > b  <=>  map(a) > map(b) (finite floats).
static __device__ __forceinline__ uint32_t fmono(float f) {
    uint32_t u = __float_as_uint(f);
    return (u & 0x80000000u) ? ~u : (u | 0x80000000u);
}
template<int N>
static __device__ __forceinline__ void waitvm() {
    if constexpr (N == 0)      asm volatile("s_waitcnt vmcnt(0)" ::: "memory");
    else if constexpr (N == 2) asm volatile("s_waitcnt vmcnt(2)" ::: "memory");
    else if constexpr (N == 3) asm volatile("s_waitcnt vmcnt(3)" ::: "memory");
    else if constexpr (N == 4) asm volatile("s_waitcnt vmcnt(4)" ::: "memory");
    else if constexpr (N == 6) asm volatile("s_waitcnt vmcnt(6)" ::: "memory");
}

#define GLD16(gp, lp)                                                          \
    __builtin_amdgcn_global_load_lds(                                         \
        (const __attribute__((address_space(1))) void*)(gp),                  \
        (__attribute__((address_space(3))) void*)(lp), 16, 0, 0)

// ---------------------------------------------------------------------------
// Paired split-bf16 GEMM step. Block (MFR*32) x (NFR*32), 4 waves (2m x 2n).
// Two compile-time phases:
//   paired tiles p<NKP : stage A-seg (64 cols) once + W-pair (128 cols);
//     compute reuses af registers across both W subtiles (hi, lo).
//   single tiles s<NKS : stage A-seg + W (64 cols) as before.
// 3 rotating buffers, counted-vmcnt pipeline (stage i+2 while computing i;
// wait = gld-count of stage i+1: GP = MFR+2*NFR, GS = MFR+NFR; per-wave
// counts identical across waves so vmcnt + s_barrier is sound).
// LDS rows: A/W-single 128B rows (8 slots, XOR row&7); W-pair 256B rows
// (16 slots, XOR row&15); global source pre-swizzled, ds_read same XOR.
// ---------------------------------------------------------------------------
template<int MFR, int NFR, int NTPX,
         int NKP, int PT1, int PO0, int PO1,
         int NKS, int ST1, int SO0, int SO1, bool GATES>
__global__ __launch_bounds__(256) void gemm_step(
    const ushort* __restrict__ A, int astr,
    const ushort* __restrict__ W, int kv,
    const float* __restrict__ bias,
    float* __restrict__ c,
    ushort* __restrict__ hdest, int ldh,
    const float* __restrict__ xsrc, ushort* __restrict__ xdest,
    float* __restrict__ out, int ldo,
    unsigned long long* __restrict__ keys)
{
    constexpr int ABUF = MFR * 2048;             // ushorts per A buffer (8KB*MFR/2)
    constexpr int WBUF = NFR * 4096;             // ushorts per W buffer (pair-size)
    __shared__ __align__(16) ushort lds[3 * ABUF + 3 * WBUF];

    const int tid = threadIdx.x;
    const int lane = tid & 63;
    const int wid = tid >> 6;
    const int wm = wid >> 1, wn = wid & 1;
    const int l15 = lane & 15, lq = lane >> 4;
    const int l7 = lane & 7, l3 = lane >> 3;

    const int flat = blockIdx.x;
    const int xcd = flat & 7, slot = flat >> 3;
    const int n_tile = xcd * NTPX + (slot % NTPX);
    const int m_tile = slot / NTPX;
    const int m0 = m_tile * (MFR * 32);
    const int n0 = n_tile * (NFR * 32);

    f32x4 acc[MFR][NFR];
#pragma unroll
    for (int m = 0; m < MFR; ++m)
#pragma unroll
        for (int n = 0; n < NFR; ++n) { f32x4 z = {0.f, 0.f, 0.f, 0.f}; acc[m][n] = z; }

    auto stageA = [&](int kcA, int bufi) {
        ushort* ab = &lds[bufi * ABUF];
#pragma unroll
        for (int i = 0; i < MFR; ++i) {
            const int rowg = (i * 4 + wid) * 8;
            const int row = rowg + l3;
            GLD16(A + (size_t)(m0 + row) * astr + kcA + ((l7 ^ (row & 7)) * 8),
                  ab + rowg * 64);
        }
    };
    auto stageP = [&](int p, int bufi) {
        stageA(p * 64 + (p < PT1 ? PO0 : PO1), bufi);
        const int kcW = p * 128;
        ushort* wb = &lds[3 * ABUF + bufi * WBUF];
#pragma unroll
        for (int i = 0; i < 2 * NFR; ++i) {      // 256B rows, 16 lanes/row
            const int rowg = (i * 4 + wid) * 4;
            const int row = rowg + lq;
            GLD16(W + (size_t)(n0 + row) * kv + kcW + ((l15 ^ (row & 15)) * 8),
                  wb + rowg * 128);
        }
    };
    auto stageS = [&](int s, int bufi) {
        stageA(s * 64 + (s < ST1 ? SO0 : SO1), bufi);
        const int kcW = NKP * 128 + s * 64;
        ushort* wb = &lds[3 * ABUF + bufi * WBUF];
#pragma unroll
        for (int i = 0; i < NFR; ++i) {          // 128B rows
            const int rowg = (i * 4 + wid) * 8;
            const int row = rowg + l3;
            GLD16(W + (size_t)(n0 + row) * kv + kcW + ((l7 ^ (row & 7)) * 8),
                  wb + rowg * 64);
        }
    };
    auto compP = [&](int bufi) {
        const ushort* ab = &lds[bufi * ABUF];
        const ushort* wb = &lds[3 * ABUF + bufi * WBUF];
#pragma unroll
        for (int kk = 0; kk < 2; ++kk) {
            short8 af[MFR];
#pragma unroll
            for (int m = 0; m < MFR; ++m) {
                const int row = wm * (MFR * 16) + m * 16 + l15;
                af[m] = *(const short8*)
                    &ab[row * 64 + (((kk * 4 + lq) ^ (row & 7)) * 8)];
            }
#pragma unroll
            for (int sub = 0; sub < 2; ++sub) {
                short8 wf[NFR];
#pragma unroll
                for (int n = 0; n < NFR; ++n) {
                    const int row = wn * (NFR * 16) + n * 16 + l15;
                    wf[n] = *(const short8*)
                        &wb[row * 128 + (((sub * 8 + kk * 4 + lq) ^ (row & 15)) * 8)];
                }
#pragma unroll
                for (int m = 0; m < MFR; ++m)
#pragma unroll
                    for (int n = 0; n < NFR; ++n)
                        acc[m][n] = __builtin_amdgcn_mfma_f32_16x16x32_bf16(
                            af[m], wf[n], acc[m][n], 0, 0, 0);
            }
        }
    };
    auto compS = [&](int bufi) {
        const ushort* ab = &lds[bufi * ABUF];
        const ushort* wb = &lds[3 * ABUF + bufi * WBUF];
#pragma unroll
        for (int kk = 0; kk < 2; ++kk) {
            short8 af[MFR], wf[NFR];
#pragma unroll
            for (int m = 0; m < MFR; ++m) {
                const int row = wm * (MFR * 16) + m * 16 + l15;
                af[m] = *(const short8*)
                    &ab[row * 64 + (((kk * 4 + lq) ^ (row & 7)) * 8)];
            }
#pragma unroll
            for (int n = 0; n < NFR; ++n) {
                const int row = wn * (NFR * 16) + n * 16 + l15;
                wf[n] = *(const short8*)
                    &wb[row * 64 + (((kk * 4 + lq) ^ (row & 7)) * 8)];
            }
#pragma unroll
            for (int m = 0; m < MFR; ++m)
#pragma unroll
                for (int n = 0; n < NFR; ++n)
                    acc[m][n] = __builtin_amdgcn_mfma_f32_16x16x32_bf16(
                        af[m], wf[n], acc[m][n], 0, 0, 0);
        }
    };

    auto STG = [&](int i, int b) { if (i < NKP) stageP(i, b); else stageS(i - NKP, b); };

    constexpr int NT = NKP + NKS;
    constexpr int GP = MFR + 2 * NFR;            // gld/wave of a paired stage
    constexpr int GS = MFR + NFR;                // gld/wave of a single stage

    STG(0, 0);
    STG(1, 1);
#pragma unroll 1
    for (int i0 = 0; i0 < NT; i0 += 3) {
#pragma unroll
        for (int j = 0; j < 3; ++j) {
            const int i = i0 + j;
            if (i < NT) {
                // wait: stage i complete; outstanding = stage i+1 only.
                if (i + 1 < NKP)     waitvm<GP>();
                else if (i + 1 < NT) waitvm<GS>();
                else                 waitvm<0>();
                __builtin_amdgcn_s_barrier();
                if (i + 2 < NT) STG(i + 2, (j + 2) % 3);
                if (i < NKP) compP(j); else compS(j);
            }
        }
    }

    // --- epilogue ----------------------------------------------------------
    if constexpr (GATES) {
        // MFR == NFR == 2 (64x64 tile). Exchange acc via LDS z-tile.
        float* zs = (float*)&lds[0];          // 64*65*4 = 16.6 KB
        __syncthreads();
#pragma unroll
        for (int m = 0; m < MFR; ++m)
#pragma unroll
            for (int n = 0; n < NFR; ++n)
#pragma unroll
                for (int r = 0; r < 4; ++r)
                    zs[(wm * 32 + m * 16 + lq * 4 + r) * 65 +
                       wn * 32 + n * 16 + l15] = acc[m][n][r];
        __syncthreads();

        const int row = tid & 63;
        const int jl0 = (tid >> 6) * 4;
        const int grow = m0 + row;
        const int jg = n_tile * 16 + jl0;
        const f32x4 bi4 = *(const f32x4*)&bias[n0 + jl0];
        const f32x4 bf4 = *(const f32x4*)&bias[n0 + 16 + jl0];
        const f32x4 bg4 = *(const f32x4*)&bias[n0 + 32 + jl0];
        const f32x4 bo4 = *(const f32x4*)&bias[n0 + 48 + jl0];
        f32x4 cv = *(f32x4*)&c[(size_t)grow * H_SZ + jg];
        ushort hh[4], hl[4];
#pragma unroll
        for (int jj = 0; jj < 4; ++jj) {
            const float zi = zs[row * 65 + jl0 + jj] + bi4[jj];
            const float zf = zs[row * 65 + 16 + jl0 + jj] + bf4[jj];
            const float zg = zs[row * 65 + 32 + jl0 + jj] + bg4[jj];
            const float zo = zs[row * 65 + 48 + jl0 + jj] + bo4[jj];
            const float ig = 1.f / (1.f + expf(-zi));
            const float fg = 1.f / (1.f + expf(-zf));
            const float gg = tanhf(zg);
            const float og = 1.f / (1.f + expf(-zo));
            const float cn = fg * cv[jj] + ig * gg;
            cv[jj] = cn;
            const float hv = og * tanhf(cn);
            hh[jj] = f2bf(hv);
            hl[jj] = f2bf(hv - bf2f(hh[jj]));
        }
        *(f32x4*)&c[(size_t)grow * H_SZ + jg] = cv;
        ushort* hd = hdest + (size_t)grow * ldh + jg;
        uint hv2[2], lv2[2];
        hv2[0] = (uint)hh[0] | ((uint)hh[1] << 16);
        hv2[1] = (uint)hh[2] | ((uint)hh[3] << 16);
        lv2[0] = (uint)hl[0] | ((uint)hl[1] << 16);
        lv2[1] = (uint)hl[2] | ((uint)hl[3] << 16);
        *(uint*)&hd[0] = hv2[0];
        *(uint*)&hd[2] = hv2[1];
        *(uint*)&hd[1024] = lv2[0];
        *(uint*)&hd[1026] = lv2[1];            // h_lo always hi_base + 1024

        if (xdest) {                            // fused x_{t+1} conversion
            const int idx = flat * 256 + tid;   // exactly B*I = 131072
            const int b = idx >> 8, i = idx & 255;
            const float v = xsrc[(size_t)b * (T_SZ * I_SZ) + i];
            const ushort hi = f2bf(v), lo = f2bf(v - bf2f(hi));
            xdest[(size_t)b * APE + i] = hi;
            xdest[(size_t)b * APE + 256 + i] = lo;
        }
    } else {
        // MFR == NFR == 1 (32x32). Store logits; fused per-row argmax.
        float vals[4];
        const int col = n0 + wn * 16 + l15;
        const float bv = bias[col];
#pragma unroll
        for (int r = 0; r < 4; ++r) {
            const int row = m0 + wm * 16 + lq * 4 + r;
            vals[r] = acc[0][0][r] + bv;
            out[(size_t)row * ldo + col] = vals[r];
        }
        if (keys) {
            float* zs = (float*)&lds[0];        // 32*33*4 = 4.2 KB
            __syncthreads();
#pragma unroll
            for (int r = 0; r < 4; ++r)
                zs[(wm * 16 + lq * 4 + r) * 33 + wn * 16 + l15] = vals[r];
            __syncthreads();
            if (tid < 32) {
                const int row = tid;
                float best = zs[row * 33];
                int bc = 0;
#pragma unroll
                for (int cc = 1; cc < 32; ++cc) {
                    const float x = zs[row * 33 + cc];
                    if (x > best) { best = x; bc = cc; }   // strict > : earliest col
                }
                const unsigned long long key =
                    ((unsigned long long)fmono(best) << 32) |
                    (unsigned long long)(V_SZ - 1 - (n0 + bc));
                atomicMax(&keys[m0 + row], key);
            }
        }
    }
}

// ---------------------------------------------------------------------------
// Gather: read per-row argmax key -> embed row -> xc of next dec A buffer;
// reset key to 0 for the next step (same-wave read-before-write).
// ---------------------------------------------------------------------------
__global__ __launch_bounds__(256) void gather_embed(
    unsigned long long* __restrict__ keys,
    const float* __restrict__ embed_W,
    ushort* __restrict__ xdest)
{
    const int idx = blockIdx.x * 256 + threadIdx.x;   // < 4096
    const int b = idx >> 3, e = idx & 7;
    const unsigned long long key = keys[b];
    const int yb = V_SZ - 1 - (int)(key & 0xffffffffu);
    const float v = embed_W[(size_t)yb * E_SZ + e];
    const ushort hi = f2bf(v), lo = f2bf(v - bf2f(hi));
    ushort* xd = xdest + (size_t)b * APD;
    xd[e] = hi;
    xd[8 + e] = hi;
    xd[16 + e] = lo;
    if (e == 0) keys[b] = 0ull;                 // after the wave's reads
}

// ---------------------------------------------------------------------------
// Weight packing (gate-permuted rows n' = jhi*64 + g*16 + jlo), paired cols.
// ---------------------------------------------------------------------------
__global__ void pack_enc(const float* __restrict__ Wih, const float* __restrict__ Whh,
                         const float* __restrict__ b, ushort* __restrict__ Wp,
                         float* __restrict__ bp)
{
    const int k = blockIdx.x * 256 + threadIdx.x;   // < 3840
    const int np = blockIdx.y;                      // < 4096
    const int orig = ((np >> 4) & 3) * H_SZ + (np >> 6) * 16 + (np & 15);
    float v; bool lo = false;
    if (k < 2560) {                                  // paired region
        const int p = k >> 7, cc = k & 63;
        lo = (k >> 6) & 1;
        v = (p < 4) ? Wih[(size_t)orig * I_SZ + p * 64 + cc]
                    : Whh[(size_t)orig * H_SZ + (p - 4) * 64 + cc];
    } else {                                         // single region (W_hi)
        const int s = (k - 2560) >> 6, cc = k & 63;
        v = (s < 4) ? Wih[(size_t)orig * I_SZ + s * 64 + cc]
                    : Whh[(size_t)orig * H_SZ + (s - 4) * 64 + cc];
    }
    const ushort hi = f2bf(v);
    Wp[(size_t)np * KVE + k] = lo ? f2bf(v - bf2f(hi)) : hi;
    if (k == 0) bp[np] = b[orig];
}

__global__ void pack_dec(const float* __restrict__ Wih, const float* __restrict__ Whh,
                         const float* __restrict__ b, ushort* __restrict__ Wp,
                         float* __restrict__ bp)
{
    const int k = blockIdx.x * 256 + threadIdx.x;
    const int np = blockIdx.y;
    if (k >= KVD) return;                            // KVD = 3200
    const int orig = ((np >> 4) & 3) * H_SZ + (np >> 6) * 16 + (np & 15);
    float v = 0.f; bool lo = false; bool zero = false;
    if (k < 2048) {                                  // paired: Whh hi|lo
        const int p = k >> 7, cc = k & 63;
        lo = (k >> 6) & 1;
        v = Whh[(size_t)orig * H_SZ + p * 64 + cc];
    } else {
        const int s = (k - 2048) >> 6, cc = k & 63;
        if (s < 2) {                                 // xc tiles (pre-expanded)
            const int j = s * 64 + cc;
            if (j < 8)       v = Wih[(size_t)orig * E_SZ + j];
            else if (j < 16) { v = Wih[(size_t)orig * E_SZ + j - 8]; lo = true; }
            else if (j < 24) v = Wih[(size_t)orig * E_SZ + j - 16];
            else             zero = true;
        } else {                                     // h_lo singles: Whh_hi
            v = Whh[(size_t)orig * H_SZ + (s - 2) * 64 + cc];
        }
    }
    ushort w = 0;
    if (!zero) { const ushort hi = f2bf(v); w = lo ? f2bf(v - bf2f(hi)) : hi; }
    Wp[(size_t)np * KVD + k] = w;
    if (k == 0) bp[np] = b[orig];
}

__global__ void pack_fc(const float* __restrict__ W, ushort* __restrict__ Wp)
{
    const int k = blockIdx.x * 256 + threadIdx.x;   // < 3072
    const int np = blockIdx.y;                      // < 1024 (no permute)
    float v; bool lo = false;
    if (k < 2048) {
        const int p = k >> 7, cc = k & 63;
        lo = (k >> 6) & 1;
        v = W[(size_t)np * H_SZ + p * 64 + cc];
    } else {
        const int s = (k - 2048) >> 6, cc = k & 63;
        v = W[(size_t)np * H_SZ + s * 64 + cc];
    }
    const ushort hi = f2bf(v);
    Wp[(size_t)np * KVF + k] = lo ? f2bf(v - bf2f(hi)) : hi;
}

// ---------------------------------------------------------------------------
// Init: zero c + A_enc0 h region; convert x(0); xc(0) from embed row 0;
// zero dec xc pads (both buffers); zero argmax keys.
// ---------------------------------------------------------------------------
__global__ void init_all(const float* __restrict__ x0,
                         const float* __restrict__ embed_W,
                         float* __restrict__ c,
                         ushort* __restrict__ Aenc0,
                         ushort* __restrict__ Adec0,
                         ushort* __restrict__ Adec1,
                         unsigned long long* __restrict__ keys)
{
    const int idx = blockIdx.x * 256 + threadIdx.x;   // < 512*2048
    {
        const int b = idx >> 11, k = idx & 2047;
        Aenc0[(size_t)b * APE + 512 + k] = 0;
    }
    if (idx < B_SZ * H_SZ) c[idx] = 0.f;
    if (idx < B_SZ) keys[idx] = 0ull;
    if (idx < B_SZ * I_SZ) {
        const int b = idx >> 8, i = idx & 255;
        const float v = x0[(size_t)b * (T_SZ * I_SZ) + i];
        const ushort hi = f2bf(v), lo = f2bf(v - bf2f(hi));
        Aenc0[(size_t)b * APE + i] = hi;
        Aenc0[(size_t)b * APE + 256 + i] = lo;
    }
    if (idx < B_SZ * 104) {
        const int b = idx / 104, col = 24 + idx % 104;
        Adec0[(size_t)b * APD + col] = 0;
        Adec1[(size_t)b * APD + col] = 0;
    }
    if (idx < B_SZ * 24) {
        const int b = idx / 24, col = idx % 24;
        float v;
        if (col < 8)       v = embed_W[col];
        else if (col < 16) v = embed_W[col - 8];
        else               v = embed_W[col - 16];
        const ushort hi = f2bf(v);
        Adec0[(size_t)b * APD + col] = (col < 16) ? hi : f2bf(v - bf2f(hi));
    }
}

extern "C" void kernel_launch(void* const* d_in, const int* in_sizes, int n_in,
                              void* d_out, int out_size, void* d_ws, size_t ws_size,
                              hipStream_t stream)
{
    const float* x_hist  = (const float*)d_in[0];
    const float* enc_Wih = (const float*)d_in[1];
    const float* enc_Whh = (const float*)d_in[2];
    const float* enc_b   = (const float*)d_in[3];
    const float* embed_W = (const float*)d_in[4];
    const float* dec_Wih = (const float*)d_in[5];
    const float* dec_Whh = (const float*)d_in[6];
    const float* dec_b   = (const float*)d_in[7];
    const float* fc_W    = (const float*)d_in[8];
    const float* fc_b    = (const float*)d_in[9];
    float* out = (float*)d_out;

    char* p = (char*)d_ws;
    auto alloc = [&](size_t bytes) {
        char* r = p;
        p += (bytes + 255) & ~(size_t)255;
        return r;
    };
    ushort* W_enc  = (ushort*)alloc((size_t)4096 * KVE * 2);   // 30 MB
    ushort* W_dec  = (ushort*)alloc((size_t)4096 * KVD * 2);   // 25 MB
    ushort* W_fc   = (ushort*)alloc((size_t)1024 * KVF * 2);   // 6 MB
    ushort* A_enc0 = (ushort*)alloc((size_t)B_SZ * APE * 2);   // 2.5 MB
    ushort* A_enc1 = (ushort*)alloc((size_t)B_SZ * APE * 2);
    ushort* A_dec0 = (ushort*)alloc((size_t)B_SZ * APD * 2);   // 2.13 MB
    ushort* A_dec1 = (ushort*)alloc((size_t)B_SZ * APD * 2);
    float*  cbuf   = (float*)alloc((size_t)B_SZ * H_SZ * 4);   // 2 MB
    float*  bpe    = (float*)alloc(4096 * 4);
    float*  bpd    = (float*)alloc(4096 * 4);
    unsigned long long* keys = (unsigned long long*)alloc(B_SZ * 8);

    const dim3 blk(256);
    hipLaunchKernelGGL(pack_enc, dim3(15, 4096), blk, 0, stream, enc_Wih, enc_Whh, enc_b, W_enc, bpe);
    hipLaunchKernelGGL(pack_dec, dim3(13, 4096), blk, 0, stream, dec_Wih, dec_Whh, dec_b, W_dec, bpd);
    hipLaunchKernelGGL(pack_fc,  dim3(12, 1024), blk, 0, stream, fc_W, W_fc);
    hipLaunchKernelGGL(init_all, dim3(4096), blk, 0, stream, x_hist, embed_W, cbuf, A_enc0, A_dec0, A_dec1, keys);

    ushort* Ae[2] = {A_enc0, A_enc1};
    ushort* Ad[2] = {A_dec0, A_dec1};

    // Encoder. Paired p: A col = 64p + (p<4 ? 0 : 256)  [x_hi, h_hi]
    //          Single s: A col = 64s + (s<4 ? 256 : 1280) [x_lo, h_lo]
    for (int t = 0; t < T_SZ; ++t) {
        ushort* hdst; int ldh; const float* xs; ushort* xd;
        if (t < T_SZ - 1) {
            hdst = Ae[(t + 1) & 1] + 512; ldh = APE;
            xs = x_hist + (size_t)(t + 1) * I_SZ;
            xd = Ae[(t + 1) & 1];
        } else {
            hdst = Ad[0] + 128; ldh = APD;
            xs = nullptr; xd = nullptr;
        }
        hipLaunchKernelGGL((gemm_step<2, 2, 8, 20, 4, 0, 256, 20, 4, 256, 1280, true>),
                           dim3(512), blk, 0, stream,
                           Ae[t & 1], APE, W_enc, KVE, bpe, cbuf,
                           hdst, ldh, xs, xd, (float*)nullptr, 0,
                           (unsigned long long*)nullptr);
    }

    // Decoder. Paired p: A col = 64p + 128 [h_hi].
    //          Single s: A col = 64s + (s<2 ? 0 : 1024) [xc, h_lo].
    // fc:      Paired p: A col = 64p + 128 [h_hi]; Single s: 64s + 1152 [h_lo].
    for (int t = 0; t < FUT; ++t) {
        hipLaunchKernelGGL((gemm_step<2, 2, 8, 16, 16, 128, 128, 18, 2, 0, 1024, true>),
                           dim3(512), blk, 0, stream,
                           Ad[t & 1], APD, W_dec, KVD, bpd, cbuf,
                           Ad[(t + 1) & 1] + 128, APD,
                           (const float*)nullptr, (ushort*)nullptr,
                           (float*)nullptr, 0,
                           (unsigned long long*)nullptr);
        float* logits = out + (size_t)t * V_SZ;   // [B, FUT, V]
        hipLaunchKernelGGL((gemm_step<1, 1, 4, 16, 16, 128, 128, 16, 16, 1152, 1152, false>),
                           dim3(512), blk, 0, stream,
                           Ad[(t + 1) & 1], APD, W_fc, KVF, fc_b,
                           (float*)nullptr, (ushort*)nullptr, 0,
                           (const float*)nullptr, (ushort*)nullptr,
                           logits, FUT * V_SZ, keys);
        hipLaunchKernelGGL(gather_embed, dim3(16), blk, 0, stream,
                           keys, embed_W, Ad[(t + 1) & 1]);
    }
}